// Round 17
// baseline (306.342 us; speedup 1.0000x reference)
//
#include <hip/hip_runtime.h>
#include <math.h>

#define NEG_SLOPE 0.2f
#define BN_EPS 1e-5f
#define BSHIFT 7
#define BSIZE 128          // nodes per bucket
#define NBMAX 512          // max buckets supported (n <= 65536)
#define BIN_CHUNK 8192
#define SCOP 8             // hashed stats copies for colstats

typedef short v8s __attribute__((ext_vector_type(8)));   // 8 bf16 (4 VGPRs)
typedef float v4f __attribute__((ext_vector_type(4)));   // 4 fp32 acc

static __device__ __forceinline__ float wave_red_sum(float v) {
    for (int off = 32; off; off >>= 1) v += __shfl_xor(v, off);
    return v;
}

// fp32 -> bf16 bits, round-to-nearest-even
static __device__ __forceinline__ unsigned short f2bf(float f) {
    unsigned int u = __float_as_uint(f);
    unsigned int r = u + 0x7FFFu + ((u >> 16) & 1u);
    return (unsigned short)(r >> 16);
}

static __device__ __forceinline__ float bf2f(unsigned short b) {
    return __uint_as_float(((unsigned int)b) << 16);
}

static __device__ __forceinline__ unsigned int pack2(float a, float b) {
    return (unsigned int)f2bf(a) | ((unsigned int)f2bf(b) << 16);
}

// hi/lo bf16 split: x ~= hi + lo, |err| ~ 2^-16 relative
static __device__ __forceinline__ void bfsplit(float x, unsigned short& h, unsigned short& l) {
    h = f2bf(x);
    l = f2bf(x - bf2f(h));
}

// ---------------- binned CSR build ----------------
__global__ void k_zero(int* p, int m) {
    int i = blockIdx.x * blockDim.x + threadIdx.x;
    if (i < m) p[i] = 0;
}

__global__ void __launch_bounds__(256) k_bucket_count(const int* __restrict__ dst, int E4,
                                                      int* __restrict__ bcnt) {
    __shared__ int lc[NBMAX];
    for (int i = threadIdx.x; i < NBMAX; i += 256) lc[i] = 0;
    __syncthreads();
    const int4* d4 = (const int4*)dst;
    int stride = gridDim.x * blockDim.x;
    for (int i = blockIdx.x * blockDim.x + threadIdx.x; i < E4; i += stride) {
        int4 v = d4[i];
        atomicAdd(&lc[v.x >> BSHIFT], 1);
        atomicAdd(&lc[v.y >> BSHIFT], 1);
        atomicAdd(&lc[v.z >> BSHIFT], 1);
        atomicAdd(&lc[v.w >> BSHIFT], 1);
    }
    __syncthreads();
    for (int i = threadIdx.x; i < NBMAX; i += 256)
        if (lc[i] > 0) atomicAdd(&bcnt[i], lc[i]);
}

__global__ void __launch_bounds__(256) k_bucket_scan(const int* __restrict__ bcnt, int NB,
                                                     int* __restrict__ bstart,
                                                     int* __restrict__ gcursor) {
    __shared__ int wsum[256];
    int tid = threadIdx.x;
    int i0 = tid * 2, i1 = tid * 2 + 1;
    int v0 = bcnt[i0], v1 = bcnt[i1];
    int s = v0 + v1;
    wsum[tid] = s;
    __syncthreads();
    for (int off = 1; off < 256; off <<= 1) {
        int t = (tid >= off) ? wsum[tid - off] : 0;
        __syncthreads();
        wsum[tid] += t;
        __syncthreads();
    }
    int excl = wsum[tid] - s;
    if (i0 < NB) { bstart[i0] = excl; gcursor[i0] = excl; }
    excl += v0;
    if (i1 < NB) { bstart[i1] = excl; gcursor[i1] = excl; }
    if (tid == 255) bstart[NB] = wsum[255];
}

// bin edges into per-bucket streams, PACKED: (src << BSHIFT) | (dst & (BSIZE-1))
__global__ void __launch_bounds__(256) k_bin(const int* __restrict__ src,
                                             const int* __restrict__ dst, int E,
                                             int* __restrict__ gcursor,
                                             unsigned int* __restrict__ binned) {
    __shared__ int lc[NBMAX], lbase[NBMAX];
    int e0 = blockIdx.x * BIN_CHUNK;
    int e1 = min(e0 + BIN_CHUNK, E);
    for (int i = threadIdx.x; i < NBMAX; i += 256) lc[i] = 0;
    __syncthreads();
    for (int i = e0 + threadIdx.x; i < e1; i += 256)
        atomicAdd(&lc[dst[i] >> BSHIFT], 1);
    __syncthreads();
    for (int i = threadIdx.x; i < NBMAX; i += 256) {
        int c = lc[i];
        if (c > 0) lbase[i] = atomicAdd(&gcursor[i], c);
    }
    __syncthreads();
    for (int i = threadIdx.x; i < NBMAX; i += 256) lc[i] = 0;
    __syncthreads();
    for (int i = e0 + threadIdx.x; i < e1; i += 256) {
        int d = dst[i];
        int b = d >> BSHIFT;
        int pos = lbase[b] + atomicAdd(&lc[b], 1);
        binned[pos] = ((unsigned int)src[i] << BSHIFT) | (unsigned int)(d & (BSIZE - 1));
    }
}

__global__ void __launch_bounds__(256) k_bucket_csr(
    const unsigned int* __restrict__ binned, const int* __restrict__ bstart, int n, int NB,
    int* __restrict__ row_ptr, int* __restrict__ csr_src) {
    __shared__ int cnt[BSIZE];
    __shared__ int wsum[BSIZE];
    int b = blockIdx.x;
    int node0 = b << BSHIFT;
    int nnodes = min(BSIZE, n - node0);
    int tid = threadIdx.x;
    if (tid < BSIZE) cnt[tid] = (tid < nnodes) ? 1 : 0;  // self loop
    __syncthreads();
    int ebeg = bstart[b], eend = bstart[b + 1];
    for (int i = ebeg + tid; i < eend; i += 256)
        atomicAdd(&cnt[binned[i] & (BSIZE - 1)], 1);
    __syncthreads();
    int c = 0;
    if (tid < BSIZE) { c = cnt[tid]; wsum[tid] = c; }
    __syncthreads();
    for (int off = 1; off < BSIZE; off <<= 1) {
        int t = (tid >= off && tid < BSIZE) ? wsum[tid - off] : 0;
        __syncthreads();
        if (tid < BSIZE) wsum[tid] += t;
        __syncthreads();
    }
    int csr_base = ebeg + node0;
    if (tid < BSIZE) {
        int excl = wsum[tid] - c;
        int node = node0 + tid;
        if (tid < nnodes) {
            row_ptr[node] = csr_base + excl;
            csr_src[csr_base + excl] = node;  // self loop first
        }
        cnt[tid] = excl + 1;
    }
    if (b == NB - 1 && tid == BSIZE - 1) row_ptr[n] = csr_base + wsum[BSIZE - 1];
    __syncthreads();
    for (int i = ebeg + tid; i < eend; i += 256) {
        unsigned int e2 = binned[i];
        int pos = csr_base + atomicAdd(&cnt[e2 & (BSIZE - 1)], 1);
        csr_src[pos] = (int)(e2 >> BSHIFT);
    }
}

// ---------------- MFMA per-layer GEMM (bf16x3, fp32-quality): H(bf16)=act(X)@W ----
// Block = 64 nodes, 4 waves; wave = 16 nodes x 64 feats. X/W^T staged as bf16
// HI/LO pairs (XOR-swizzled); acc += Ah*Bh + Ah*Bl + Al*Bh. XEXACT (bf16 input,
// no BN): X lo == 0 exactly -> skip Xo staging + Al*Bh MFMA (exact fast path).
template <int FIN, int USE_BN, int XBF16>
__global__ void __launch_bounds__(256) k_gemm(
    const void* __restrict__ Xv, const float* __restrict__ W,
    const float* __restrict__ a_src, const float* __restrict__ a_dst,
    const float* __restrict__ stats, const float* __restrict__ gam,
    const float* __restrict__ bet, float inv_n,
    unsigned short* __restrict__ H16, float* __restrict__ S, float* __restrict__ Dv, int n) {
    constexpr bool XEXACT = (XBF16 && !USE_BN);
    constexpr int RS = FIN * 2;                  // row stride (bytes) per tile
    __shared__ unsigned int Xh[64 * FIN / 2];    // bf16 hi [64 nodes][FIN], swizzled
    __shared__ unsigned int Xo[XEXACT ? 64 : 64 * FIN / 2];  // bf16 lo (unused if XEXACT)
    __shared__ unsigned int Wh[64 * FIN / 2];    // bf16 hi W^T [64 feat][FIN k]
    __shared__ unsigned int Wo[64 * FIN / 2];    // bf16 lo
    __shared__ float bn_sc[64], bn_sh[64], sred[128];
    const int t = threadIdx.x;
    const int node0 = blockIdx.x * 64;

    if (USE_BN) {
        if (t < 128) {
            float a = 0.f;
            #pragma unroll
            for (int c = 0; c < SCOP; c++) a += stats[c * 128 + t];
            sred[t] = a;
        }
        __syncthreads();
        if (t < 64) {
            float mu = sred[t] * inv_n;
            float var = sred[64 + t] * inv_n - mu * mu;
            float rstd = rsqrtf(var + BN_EPS);
            float sc = rstd * gam[t];
            bn_sc[t] = sc;
            bn_sh[t] = bet[t] - mu * sc;
        }
        __syncthreads();
    }

    // ---- stage X (+BN+ReLU) -> hi/lo bf16, swizzled ----
    if (XBF16) {
        const unsigned int* X2 = (const unsigned int*)Xv;
        constexpr int NU = FIN / 2;              // uints per row
        for (int idx = t; idx < 64 * NU; idx += 256) {
            int r = idx / NU, c2 = idx % NU;
            unsigned int u = 0;
            if (node0 + r < n) u = X2[(size_t)(node0 + r) * NU + c2];
            int byte = r * RS + c2 * 4;
            int sw = (byte ^ ((r & 7) << 4)) >> 2;
            if constexpr (XEXACT) {
                Xh[sw] = u;                      // already exact bf16 pair
            } else {
                float a = __uint_as_float(u << 16);
                float b = __uint_as_float(u & 0xFFFF0000u);
                if (USE_BN) {
                    int k = c2 * 2;
                    a = fmaxf(fmaf(a, bn_sc[k + 0], bn_sh[k + 0]), 0.f);
                    b = fmaxf(fmaf(b, bn_sc[k + 1], bn_sh[k + 1]), 0.f);
                }
                unsigned short ha, la, hb, lb;
                bfsplit(a, ha, la); bfsplit(b, hb, lb);
                Xh[sw] = (unsigned int)ha | ((unsigned int)hb << 16);
                Xo[sw] = (unsigned int)la | ((unsigned int)lb << 16);
            }
        }
    } else {
        const float4* X4 = (const float4*)Xv;
        constexpr int NF4 = FIN / 4;
        for (int idx = t; idx < 64 * NF4; idx += 256) {
            int r = idx / NF4, c4 = idx % NF4;
            float4 v = make_float4(0.f, 0.f, 0.f, 0.f);
            if (node0 + r < n) v = X4[(size_t)(node0 + r) * NF4 + c4];
            if (USE_BN) {
                int k = c4 * 4;
                v.x = fmaxf(fmaf(v.x, bn_sc[k + 0], bn_sh[k + 0]), 0.f);
                v.y = fmaxf(fmaf(v.y, bn_sc[k + 1], bn_sh[k + 1]), 0.f);
                v.z = fmaxf(fmaf(v.z, bn_sc[k + 2], bn_sh[k + 2]), 0.f);
                v.w = fmaxf(fmaf(v.w, bn_sc[k + 3], bn_sh[k + 3]), 0.f);
            }
            unsigned short hx, lx, hy, ly, hz, lz, hw, lw;
            bfsplit(v.x, hx, lx); bfsplit(v.y, hy, ly);
            bfsplit(v.z, hz, lz); bfsplit(v.w, hw, lw);
            int byte = r * RS + c4 * 8;
            int sw = (byte ^ ((r & 7) << 4)) >> 2;
            Xh[sw + 0] = (unsigned int)hx | ((unsigned int)hy << 16);
            Xh[sw + 1] = (unsigned int)hz | ((unsigned int)hw << 16);
            Xo[sw + 0] = (unsigned int)lx | ((unsigned int)ly << 16);
            Xo[sw + 1] = (unsigned int)lz | ((unsigned int)lw << 16);
        }
    }
    // ---- stage W^T -> hi/lo bf16, swizzled (W global is [FIN k][64 feat]) ----
    for (int idx = t; idx < FIN * 32; idx += 256) {
        int feat = idx & 63;
        int k2 = (idx >> 6) * 2;
        float w0 = W[(size_t)k2 * 64 + feat];
        float w1 = W[(size_t)(k2 + 1) * 64 + feat];
        unsigned short h0, l0, h1, l1;
        bfsplit(w0, h0, l0); bfsplit(w1, h1, l1);
        int byte = feat * RS + k2 * 2;
        int sw = (byte ^ ((feat & 7) << 4)) >> 2;
        Wh[sw] = (unsigned int)h0 | ((unsigned int)h1 << 16);
        Wo[sw] = (unsigned int)l0 | ((unsigned int)l1 << 16);
    }
    __syncthreads();

    const int wave = t >> 6, lane = t & 63;
    const int g = lane >> 4, li = lane & 15;
    const int nbase = wave * 16;

    v4f acc[4];
    #pragma unroll
    for (int f = 0; f < 4; f++) acc[f] = (v4f){0.f, 0.f, 0.f, 0.f};

    const int rowA = nbase + li;
    #pragma unroll
    for (int kc = 0; kc < FIN / 32; kc++) {
        int offA = (rowA * RS + kc * 64 + g * 16) ^ ((rowA & 7) << 4);
        v8s ah = *(const v8s*)((const char*)Xh + offA);
        v8s al{};
        if constexpr (!XEXACT) al = *(const v8s*)((const char*)Xo + offA);
        #pragma unroll
        for (int f = 0; f < 4; f++) {
            int rowW = f * 16 + li;
            int offB = (rowW * RS + kc * 64 + g * 16) ^ ((rowW & 7) << 4);
            v8s bh = *(const v8s*)((const char*)Wh + offB);
            v8s bl = *(const v8s*)((const char*)Wo + offB);
            acc[f] = __builtin_amdgcn_mfma_f32_16x16x32_bf16(ah, bh, acc[f], 0, 0, 0);
            acc[f] = __builtin_amdgcn_mfma_f32_16x16x32_bf16(ah, bl, acc[f], 0, 0, 0);
            if constexpr (!XEXACT)
                acc[f] = __builtin_amdgcn_mfma_f32_16x16x32_bf16(al, bh, acc[f], 0, 0, 0);
        }
    }

    // ---- epilogue: H bf16 stores + per-node score dots (16-lane group reduce) ----
    float as_[4], ad_[4];
    #pragma unroll
    for (int f = 0; f < 4; f++) { as_[f] = a_src[f * 16 + li]; ad_[f] = a_dst[f * 16 + li]; }
    #pragma unroll
    for (int j = 0; j < 4; j++) {
        int node = node0 + nbase + g * 4 + j;
        float ps = acc[0][j] * as_[0] + acc[1][j] * as_[1] +
                   acc[2][j] * as_[2] + acc[3][j] * as_[3];
        float pd = acc[0][j] * ad_[0] + acc[1][j] * ad_[1] +
                   acc[2][j] * ad_[2] + acc[3][j] * ad_[3];
        #pragma unroll
        for (int m = 1; m < 16; m <<= 1) {
            ps += __shfl_xor(ps, m);
            pd += __shfl_xor(pd, m);
        }
        if (node < n) {
            #pragma unroll
            for (int f = 0; f < 4; f++)
                H16[(size_t)node * 64 + f * 16 + li] = f2bf(acc[f][j]);
            if (li == 0) { S[node] = ps; Dv[node] = pd; }
        }
    }
}

// ---------------- node-parallel GAT aggregate (bf16 H gather, 16 loads in flight) --
// Wave = 1 node; half-wave per edge (32 lanes x 1 uint = 128B coalesced row).
// Inner loop: 32 edges / 16 independent H-row loads per iteration -- most nodes
// (deg~26) finish the gather in ONE iteration with all rows in flight at once.
// Branchless tail: lanes >= cnt carry w=0; min(idx,63) shfl lands on such lanes,
// their loads hit row 0 harmlessly and contribute 0.
// BF16OUT=1: write packed bf16 rows to out16 (mid-layer T); else fp32 to outf.
template <int BF16OUT>
__global__ void __launch_bounds__(256) k_aggregate(
    const unsigned int* __restrict__ H2, const float* __restrict__ S,
    const float* __restrict__ Dv,
    const int* __restrict__ row_ptr, const int* __restrict__ csr_src,
    const float* __restrict__ bias, float* __restrict__ outf,
    unsigned int* __restrict__ out16, int n) {
    int wave = threadIdx.x >> 6, lane = threadIdx.x & 63;
    int node = blockIdx.x * 4 + wave;
    if (node >= n) return;
    int start = row_ptr[node], end = row_ptr[node + 1];
    float dn = Dv[node];
    int half = lane >> 5;
    int col = lane & 31;
    float accL0 = 0.f, accH0 = 0.f, accL1 = 0.f, accH1 = 0.f;
    float zlane = 0.f;
    for (int base = start; base < end; base += 64) {
        int cnt = min(64, end - base);
        int sj = 0;
        float w = 0.f;
        if (lane < cnt) {
            sj = csr_src[base + lane];
            float t = S[sj] + dn;
            t = (t > 0.f) ? t : NEG_SLOPE * t;
            w = __expf(t);
        }
        zlane += w;
        for (int jj = 0; jj < cnt; jj += 32) {
            float ww[16];
            int ss[16];
            #pragma unroll
            for (int e = 0; e < 16; e++) {
                int id = min(jj + 2 * e + half, 63);
                ww[e] = __shfl(w, id);     // 0 when id >= cnt
                ss[e] = __shfl(sj, id);
            }
            unsigned int uu[16];
            #pragma unroll
            for (int e = 0; e < 16; e++)
                uu[e] = H2[(size_t)ss[e] * 32 + col];
            #pragma unroll
            for (int e = 0; e < 16; e++) {
                float lo = __uint_as_float(uu[e] << 16);
                float hi = __uint_as_float(uu[e] & 0xFFFF0000u);
                if (e & 1) {
                    accL1 = fmaf(ww[e], lo, accL1);
                    accH1 = fmaf(ww[e], hi, accH1);
                } else {
                    accL0 = fmaf(ww[e], lo, accL0);
                    accH0 = fmaf(ww[e], hi, accH0);
                }
            }
        }
    }
    float z = wave_red_sum(zlane);
    float accL = accL0 + accL1;
    float accH = accH0 + accH1;
    accL += __shfl_xor(accL, 32);
    accH += __shfl_xor(accH, 32);
    if (half == 0) {
        float2 b2 = ((const float2*)bias)[col];
        float ox = accL / z + b2.x;
        float oy = accH / z + b2.y;
        if (BF16OUT) {
            out16[(size_t)node * 32 + col] = pack2(ox, oy);
        } else {
            float2 o; o.x = ox; o.y = oy;
            ((float2*)outf)[(size_t)node * 32 + col] = o;
        }
    }
}

// ---------------- column stats (sum/sumsq) of bf16 T, SCOP-hashed atomics ----------
__global__ void __launch_bounds__(256) k_colstats16(const unsigned int* __restrict__ T2,
                                                    int n, float* __restrict__ stats) {
    __shared__ float s0a[256], s1a[256], q0a[256], q1a[256];
    int f2 = threadIdx.x & 31;
    int rowgrp = threadIdx.x >> 5;
    float s0 = 0.f, s1 = 0.f, q0 = 0.f, q1 = 0.f;
    for (int r = blockIdx.x * 8 + rowgrp; r < n; r += gridDim.x * 8) {
        unsigned int u = T2[(size_t)r * 32 + f2];
        float a = __uint_as_float(u << 16);
        float b = __uint_as_float(u & 0xFFFF0000u);
        s0 += a; q0 += a * a;
        s1 += b; q1 += b * b;
    }
    s0a[threadIdx.x] = s0; s1a[threadIdx.x] = s1;
    q0a[threadIdx.x] = q0; q1a[threadIdx.x] = q1;
    __syncthreads();
    for (int off = 128; off >= 32; off >>= 1) {
        if (threadIdx.x < off) {
            s0a[threadIdx.x] += s0a[threadIdx.x + off];
            s1a[threadIdx.x] += s1a[threadIdx.x + off];
            q0a[threadIdx.x] += q0a[threadIdx.x + off];
            q1a[threadIdx.x] += q1a[threadIdx.x + off];
        }
        __syncthreads();
    }
    if (threadIdx.x < 32) {
        float* sb = stats + ((blockIdx.x & (SCOP - 1)) << 7);
        atomicAdd(&sb[2 * threadIdx.x + 0], s0a[threadIdx.x]);
        atomicAdd(&sb[2 * threadIdx.x + 1], s1a[threadIdx.x]);
        atomicAdd(&sb[64 + 2 * threadIdx.x + 0], q0a[threadIdx.x]);
        atomicAdd(&sb[64 + 2 * threadIdx.x + 1], q1a[threadIdx.x]);
    }
}

extern "C" void kernel_launch(void* const* d_in, const int* in_sizes, int n_in,
                              void* d_out, int out_size, void* d_ws, size_t ws_size,
                              hipStream_t stream) {
    const float* x        = (const float*)d_in[0];
    const int*   ei       = (const int*)d_in[1];
    const float* W_in     = (const float*)d_in[2];
    const float* a_src_in = (const float*)d_in[3];
    const float* a_dst_in = (const float*)d_in[4];
    const float* b_in     = (const float*)d_in[5];
    const float* W_mid    = (const float*)d_in[6];
    const float* a_src_mid= (const float*)d_in[7];
    const float* a_dst_mid= (const float*)d_in[8];
    const float* b_mid    = (const float*)d_in[9];
    const float* gamma    = (const float*)d_in[10];
    const float* beta     = (const float*)d_in[11];
    const float* W_out    = (const float*)d_in[12];
    const float* a_src_out= (const float*)d_in[13];
    const float* a_dst_out= (const float*)d_in[14];
    const float* b_out    = (const float*)d_in[15];

    int n = in_sizes[0] / 128;   // 50000
    int E = in_sizes[1] / 2;     // 1250000
    const int* srcE = ei;
    const int* dstE = ei + E;
    int NB = (n + BSIZE - 1) >> BSHIFT;   // 391 (<= NBMAX assumed)
    float inv_n = 1.f / (float)n;

    auto alignup = [](size_t v) { return (v + 255) & ~(size_t)255; };
    char* p = (char*)d_ws;
    int* bcnt    = (int*)p; p += alignup(NBMAX * 4);
    float* stats3= (float*)p; p += alignup((size_t)3 * SCOP * 128 * 4);  // zeroed w/ bcnt
    int* bstart  = (int*)p; p += alignup((NBMAX + 1) * 4);
    int* gcursor = (int*)p; p += alignup(NBMAX * 4);
    int* row_ptr = (int*)p; p += alignup((size_t)(n + 1) * 4);
    unsigned int* binned = (unsigned int*)p; p += alignup((size_t)E * 4);
    int* csr     = (int*)p; p += alignup((size_t)(E + n) * 4);
    unsigned int* H2 = (unsigned int*)p; p += alignup((size_t)n * 32 * 4);   // bf16 [n][64]
    unsigned int* T2 = (unsigned int*)p; p += alignup((size_t)n * 32 * 4);   // bf16 T
    float* S     = (float*)p; p += alignup((size_t)n * 4);
    float* Dv    = (float*)p; p += alignup((size_t)n * 4);
    unsigned short* H16 = (unsigned short*)H2;

    // ---- zero bucket counts + 3 hashed layer-stat buffers (contiguous) ----
    int nzero = NBMAX + 3 * SCOP * 128;
    k_zero<<<(nzero + 255) / 256, 256, 0, stream>>>(bcnt, nzero);

    // ---- binned CSR build (edges identical across all 5 layers) ----
    k_bucket_count<<<256, 256, 0, stream>>>(dstE, E / 4, bcnt);
    k_bucket_scan<<<1, 256, 0, stream>>>(bcnt, NB, bstart, gcursor);
    k_bin<<<(E + BIN_CHUNK - 1) / BIN_CHUNK, 256, 0, stream>>>(srcE, dstE, E, gcursor, binned);
    k_bucket_csr<<<NB, 256, 0, stream>>>(binned, bstart, n, NB, row_ptr, csr);

    int gb = (n + 3) / 4;        // aggregate grid (4 nodes/block)
    int gg = (n + 63) / 64;      // gemm grid (64 nodes/block)

    // ---- input GAT layer (fp32 x input; bf16 T output) ----
    k_gemm<128, 0, 0><<<gg, 256, 0, stream>>>(x, W_in, a_src_in, a_dst_in,
                                              nullptr, nullptr, nullptr, 0.f,
                                              H16, S, Dv, n);
    k_aggregate<1><<<gb, 256, 0, stream>>>(H2, S, Dv, row_ptr, csr, b_in,
                                           nullptr, T2, n);

    // ---- mid layers: gemm (bf16 T input, inline BN) -> aggregate(bf16) -> colstats ----
    for (int l = 0; l < 3; l++) {
        if (l == 0)
            k_gemm<64, 0, 1><<<gg, 256, 0, stream>>>(T2, W_mid, a_src_mid, a_dst_mid,
                                                     nullptr, nullptr, nullptr, 0.f,
                                                     H16, S, Dv, n);
        else
            k_gemm<64, 1, 1><<<gg, 256, 0, stream>>>(T2, W_mid + l * 4096,
                                                     a_src_mid + l * 64, a_dst_mid + l * 64,
                                                     stats3 + (size_t)(l - 1) * SCOP * 128,
                                                     gamma + (l - 1) * 64, beta + (l - 1) * 64,
                                                     inv_n, H16, S, Dv, n);
        k_aggregate<1><<<gb, 256, 0, stream>>>(H2, S, Dv, row_ptr, csr, b_mid + l * 64,
                                               nullptr, T2, n);
        k_colstats16<<<256, 256, 0, stream>>>(T2, n, stats3 + (size_t)l * SCOP * 128);
    }

    // ---- output GAT layer (bf16 T input, inline BN; fp32 output to d_out) ----
    k_gemm<64, 1, 1><<<gg, 256, 0, stream>>>(T2, W_out, a_src_out, a_dst_out,
                                             stats3 + (size_t)2 * SCOP * 128,
                                             gamma + 2 * 64, beta + 2 * 64,
                                             inv_n, H16, S, Dv, n);
    k_aggregate<0><<<gb, 256, 0, stream>>>(H2, S, Dv, row_ptr, csr, b_out,
                                           (float*)d_out, nullptr, n);
}

// Round 18
// 284.775 us; speedup vs baseline: 1.0757x; 1.0757x over previous
//
#include <hip/hip_runtime.h>
#include <math.h>

#define NEG_SLOPE 0.2f
#define BN_EPS 1e-5f
#define BSHIFT 7
#define BSIZE 128          // nodes per bucket
#define NBMAX 512          // max buckets supported (n <= 65536)
#define BIN_CHUNK 8192
#define SCOP 8             // hashed stats copies for colstats

typedef short v8s __attribute__((ext_vector_type(8)));   // 8 bf16 (4 VGPRs)
typedef float v4f __attribute__((ext_vector_type(4)));   // 4 fp32 acc

static __device__ __forceinline__ float wave_red_sum(float v) {
    for (int off = 32; off; off >>= 1) v += __shfl_xor(v, off);
    return v;
}

// fp32 -> bf16 bits, round-to-nearest-even
static __device__ __forceinline__ unsigned short f2bf(float f) {
    unsigned int u = __float_as_uint(f);
    unsigned int r = u + 0x7FFFu + ((u >> 16) & 1u);
    return (unsigned short)(r >> 16);
}

static __device__ __forceinline__ float bf2f(unsigned short b) {
    return __uint_as_float(((unsigned int)b) << 16);
}

static __device__ __forceinline__ unsigned int pack2(float a, float b) {
    return (unsigned int)f2bf(a) | ((unsigned int)f2bf(b) << 16);
}

// hi/lo bf16 split: x ~= hi + lo, |err| ~ 2^-16 relative
static __device__ __forceinline__ void bfsplit(float x, unsigned short& h, unsigned short& l) {
    h = f2bf(x);
    l = f2bf(x - bf2f(h));
}

// ---------------- binned CSR build ----------------
__global__ void k_zero(int* p, int m) {
    int i = blockIdx.x * blockDim.x + threadIdx.x;
    if (i < m) p[i] = 0;
}

__global__ void __launch_bounds__(256) k_bucket_count(const int* __restrict__ dst, int E4,
                                                      int* __restrict__ bcnt) {
    __shared__ int lc[NBMAX];
    for (int i = threadIdx.x; i < NBMAX; i += 256) lc[i] = 0;
    __syncthreads();
    const int4* d4 = (const int4*)dst;
    int stride = gridDim.x * blockDim.x;
    for (int i = blockIdx.x * blockDim.x + threadIdx.x; i < E4; i += stride) {
        int4 v = d4[i];
        atomicAdd(&lc[v.x >> BSHIFT], 1);
        atomicAdd(&lc[v.y >> BSHIFT], 1);
        atomicAdd(&lc[v.z >> BSHIFT], 1);
        atomicAdd(&lc[v.w >> BSHIFT], 1);
    }
    __syncthreads();
    for (int i = threadIdx.x; i < NBMAX; i += 256)
        if (lc[i] > 0) atomicAdd(&bcnt[i], lc[i]);
}

__global__ void __launch_bounds__(256) k_bucket_scan(const int* __restrict__ bcnt, int NB,
                                                     int* __restrict__ bstart,
                                                     int* __restrict__ gcursor) {
    __shared__ int wsum[256];
    int tid = threadIdx.x;
    int i0 = tid * 2, i1 = tid * 2 + 1;
    int v0 = bcnt[i0], v1 = bcnt[i1];
    int s = v0 + v1;
    wsum[tid] = s;
    __syncthreads();
    for (int off = 1; off < 256; off <<= 1) {
        int t = (tid >= off) ? wsum[tid - off] : 0;
        __syncthreads();
        wsum[tid] += t;
        __syncthreads();
    }
    int excl = wsum[tid] - s;
    if (i0 < NB) { bstart[i0] = excl; gcursor[i0] = excl; }
    excl += v0;
    if (i1 < NB) { bstart[i1] = excl; gcursor[i1] = excl; }
    if (tid == 255) bstart[NB] = wsum[255];
}

// bin edges into per-bucket streams, PACKED: (src << BSHIFT) | (dst & (BSIZE-1))
// 1024 threads/block (round-17 fix: 256 threads left k_bin at 4.8% occupancy,
// 42 us, pure parallelism starvation -- 4x waves cuts per-block latency 4x).
__global__ void __launch_bounds__(1024) k_bin(const int* __restrict__ src,
                                              const int* __restrict__ dst, int E,
                                              int* __restrict__ gcursor,
                                              unsigned int* __restrict__ binned) {
    __shared__ int lc[NBMAX], lbase[NBMAX];
    int e0 = blockIdx.x * BIN_CHUNK;
    int e1 = min(e0 + BIN_CHUNK, E);
    for (int i = threadIdx.x; i < NBMAX; i += 1024) lc[i] = 0;
    __syncthreads();
    for (int i = e0 + threadIdx.x; i < e1; i += 1024)
        atomicAdd(&lc[dst[i] >> BSHIFT], 1);
    __syncthreads();
    for (int i = threadIdx.x; i < NBMAX; i += 1024) {
        int c = lc[i];
        if (c > 0) lbase[i] = atomicAdd(&gcursor[i], c);
    }
    __syncthreads();
    for (int i = threadIdx.x; i < NBMAX; i += 1024) lc[i] = 0;
    __syncthreads();
    for (int i = e0 + threadIdx.x; i < e1; i += 1024) {
        int d = dst[i];
        int b = d >> BSHIFT;
        int pos = lbase[b] + atomicAdd(&lc[b], 1);
        binned[pos] = ((unsigned int)src[i] << BSHIFT) | (unsigned int)(d & (BSIZE - 1));
    }
}

__global__ void __launch_bounds__(256) k_bucket_csr(
    const unsigned int* __restrict__ binned, const int* __restrict__ bstart, int n, int NB,
    int* __restrict__ row_ptr, int* __restrict__ csr_src) {
    __shared__ int cnt[BSIZE];
    __shared__ int wsum[BSIZE];
    int b = blockIdx.x;
    int node0 = b << BSHIFT;
    int nnodes = min(BSIZE, n - node0);
    int tid = threadIdx.x;
    if (tid < BSIZE) cnt[tid] = (tid < nnodes) ? 1 : 0;  // self loop
    __syncthreads();
    int ebeg = bstart[b], eend = bstart[b + 1];
    for (int i = ebeg + tid; i < eend; i += 256)
        atomicAdd(&cnt[binned[i] & (BSIZE - 1)], 1);
    __syncthreads();
    int c = 0;
    if (tid < BSIZE) { c = cnt[tid]; wsum[tid] = c; }
    __syncthreads();
    for (int off = 1; off < BSIZE; off <<= 1) {
        int t = (tid >= off && tid < BSIZE) ? wsum[tid - off] : 0;
        __syncthreads();
        if (tid < BSIZE) wsum[tid] += t;
        __syncthreads();
    }
    int csr_base = ebeg + node0;
    if (tid < BSIZE) {
        int excl = wsum[tid] - c;
        int node = node0 + tid;
        if (tid < nnodes) {
            row_ptr[node] = csr_base + excl;
            csr_src[csr_base + excl] = node;  // self loop first
        }
        cnt[tid] = excl + 1;
    }
    if (b == NB - 1 && tid == BSIZE - 1) row_ptr[n] = csr_base + wsum[BSIZE - 1];
    __syncthreads();
    for (int i = ebeg + tid; i < eend; i += 256) {
        unsigned int e2 = binned[i];
        int pos = csr_base + atomicAdd(&cnt[e2 & (BSIZE - 1)], 1);
        csr_src[pos] = (int)(e2 >> BSHIFT);
    }
}

// ---------------- MFMA per-layer GEMM (bf16x3, fp32-quality): H(bf16)=act(X)@W ----
// Block = 64 nodes, 4 waves; wave = 16 nodes x 64 feats. X/W^T staged as bf16
// HI/LO pairs (XOR-swizzled); acc += Ah*Bh + Ah*Bl + Al*Bh. XEXACT (bf16 input,
// no BN): X lo == 0 exactly -> skip Xo staging + Al*Bh MFMA (exact fast path).
template <int FIN, int USE_BN, int XBF16>
__global__ void __launch_bounds__(256) k_gemm(
    const void* __restrict__ Xv, const float* __restrict__ W,
    const float* __restrict__ a_src, const float* __restrict__ a_dst,
    const float* __restrict__ stats, const float* __restrict__ gam,
    const float* __restrict__ bet, float inv_n,
    unsigned short* __restrict__ H16, float* __restrict__ S, float* __restrict__ Dv, int n) {
    constexpr bool XEXACT = (XBF16 && !USE_BN);
    constexpr int RS = FIN * 2;                  // row stride (bytes) per tile
    __shared__ unsigned int Xh[64 * FIN / 2];    // bf16 hi [64 nodes][FIN], swizzled
    __shared__ unsigned int Xo[XEXACT ? 64 : 64 * FIN / 2];  // bf16 lo (unused if XEXACT)
    __shared__ unsigned int Wh[64 * FIN / 2];    // bf16 hi W^T [64 feat][FIN k]
    __shared__ unsigned int Wo[64 * FIN / 2];    // bf16 lo
    __shared__ float bn_sc[64], bn_sh[64], sred[128];
    const int t = threadIdx.x;
    const int node0 = blockIdx.x * 64;

    if (USE_BN) {
        if (t < 128) {
            float a = 0.f;
            #pragma unroll
            for (int c = 0; c < SCOP; c++) a += stats[c * 128 + t];
            sred[t] = a;
        }
        __syncthreads();
        if (t < 64) {
            float mu = sred[t] * inv_n;
            float var = sred[64 + t] * inv_n - mu * mu;
            float rstd = rsqrtf(var + BN_EPS);
            float sc = rstd * gam[t];
            bn_sc[t] = sc;
            bn_sh[t] = bet[t] - mu * sc;
        }
        __syncthreads();
    }

    // ---- stage X (+BN+ReLU) -> hi/lo bf16, swizzled ----
    if (XBF16) {
        const unsigned int* X2 = (const unsigned int*)Xv;
        constexpr int NU = FIN / 2;              // uints per row
        for (int idx = t; idx < 64 * NU; idx += 256) {
            int r = idx / NU, c2 = idx % NU;
            unsigned int u = 0;
            if (node0 + r < n) u = X2[(size_t)(node0 + r) * NU + c2];
            int byte = r * RS + c2 * 4;
            int sw = (byte ^ ((r & 7) << 4)) >> 2;
            if constexpr (XEXACT) {
                Xh[sw] = u;                      // already exact bf16 pair
            } else {
                float a = __uint_as_float(u << 16);
                float b = __uint_as_float(u & 0xFFFF0000u);
                int k = c2 * 2;
                a = fmaxf(fmaf(a, bn_sc[k + 0], bn_sh[k + 0]), 0.f);
                b = fmaxf(fmaf(b, bn_sc[k + 1], bn_sh[k + 1]), 0.f);
                unsigned short ha, la, hb, lb;
                bfsplit(a, ha, la); bfsplit(b, hb, lb);
                Xh[sw] = (unsigned int)ha | ((unsigned int)hb << 16);
                Xo[sw] = (unsigned int)la | ((unsigned int)lb << 16);
            }
        }
    } else {
        const float4* X4 = (const float4*)Xv;
        constexpr int NF4 = FIN / 4;
        for (int idx = t; idx < 64 * NF4; idx += 256) {
            int r = idx / NF4, c4 = idx % NF4;
            float4 v = make_float4(0.f, 0.f, 0.f, 0.f);
            if (node0 + r < n) v = X4[(size_t)(node0 + r) * NF4 + c4];
            if (USE_BN) {
                int k = c4 * 4;
                v.x = fmaxf(fmaf(v.x, bn_sc[k + 0], bn_sh[k + 0]), 0.f);
                v.y = fmaxf(fmaf(v.y, bn_sc[k + 1], bn_sh[k + 1]), 0.f);
                v.z = fmaxf(fmaf(v.z, bn_sc[k + 2], bn_sh[k + 2]), 0.f);
                v.w = fmaxf(fmaf(v.w, bn_sc[k + 3], bn_sh[k + 3]), 0.f);
            }
            unsigned short hx, lx, hy, ly, hz, lz, hw, lw;
            bfsplit(v.x, hx, lx); bfsplit(v.y, hy, ly);
            bfsplit(v.z, hz, lz); bfsplit(v.w, hw, lw);
            int byte = r * RS + c4 * 8;
            int sw = (byte ^ ((r & 7) << 4)) >> 2;
            Xh[sw + 0] = (unsigned int)hx | ((unsigned int)hy << 16);
            Xh[sw + 1] = (unsigned int)hz | ((unsigned int)hw << 16);
            Xo[sw + 0] = (unsigned int)lx | ((unsigned int)ly << 16);
            Xo[sw + 1] = (unsigned int)lz | ((unsigned int)lw << 16);
        }
    }
    // ---- stage W^T -> hi/lo bf16, swizzled (W global is [FIN k][64 feat]) ----
    for (int idx = t; idx < FIN * 32; idx += 256) {
        int feat = idx & 63;
        int k2 = (idx >> 6) * 2;
        float w0 = W[(size_t)k2 * 64 + feat];
        float w1 = W[(size_t)(k2 + 1) * 64 + feat];
        unsigned short h0, l0, h1, l1;
        bfsplit(w0, h0, l0); bfsplit(w1, h1, l1);
        int byte = feat * RS + k2 * 2;
        int sw = (byte ^ ((feat & 7) << 4)) >> 2;
        Wh[sw] = (unsigned int)h0 | ((unsigned int)h1 << 16);
        Wo[sw] = (unsigned int)l0 | ((unsigned int)l1 << 16);
    }
    __syncthreads();

    const int wave = t >> 6, lane = t & 63;
    const int g = lane >> 4, li = lane & 15;
    const int nbase = wave * 16;

    v4f acc[4];
    #pragma unroll
    for (int f = 0; f < 4; f++) acc[f] = (v4f){0.f, 0.f, 0.f, 0.f};

    const int rowA = nbase + li;
    #pragma unroll
    for (int kc = 0; kc < FIN / 32; kc++) {
        int offA = (rowA * RS + kc * 64 + g * 16) ^ ((rowA & 7) << 4);
        v8s ah = *(const v8s*)((const char*)Xh + offA);
        v8s al{};
        if constexpr (!XEXACT) al = *(const v8s*)((const char*)Xo + offA);
        #pragma unroll
        for (int f = 0; f < 4; f++) {
            int rowW = f * 16 + li;
            int offB = (rowW * RS + kc * 64 + g * 16) ^ ((rowW & 7) << 4);
            v8s bh = *(const v8s*)((const char*)Wh + offB);
            v8s bl = *(const v8s*)((const char*)Wo + offB);
            acc[f] = __builtin_amdgcn_mfma_f32_16x16x32_bf16(ah, bh, acc[f], 0, 0, 0);
            acc[f] = __builtin_amdgcn_mfma_f32_16x16x32_bf16(ah, bl, acc[f], 0, 0, 0);
            if constexpr (!XEXACT)
                acc[f] = __builtin_amdgcn_mfma_f32_16x16x32_bf16(al, bh, acc[f], 0, 0, 0);
        }
    }

    // ---- epilogue: H bf16 stores + per-node score dots (16-lane group reduce) ----
    float as_[4], ad_[4];
    #pragma unroll
    for (int f = 0; f < 4; f++) { as_[f] = a_src[f * 16 + li]; ad_[f] = a_dst[f * 16 + li]; }
    #pragma unroll
    for (int j = 0; j < 4; j++) {
        int node = node0 + nbase + g * 4 + j;
        float ps = acc[0][j] * as_[0] + acc[1][j] * as_[1] +
                   acc[2][j] * as_[2] + acc[3][j] * as_[3];
        float pd = acc[0][j] * ad_[0] + acc[1][j] * ad_[1] +
                   acc[2][j] * ad_[2] + acc[3][j] * ad_[3];
        #pragma unroll
        for (int m = 1; m < 16; m <<= 1) {
            ps += __shfl_xor(ps, m);
            pd += __shfl_xor(pd, m);
        }
        if (node < n) {
            #pragma unroll
            for (int f = 0; f < 4; f++)
                H16[(size_t)node * 64 + f * 16 + li] = f2bf(acc[f][j]);
            if (li == 0) { S[node] = ps; Dv[node] = pd; }
        }
    }
}

// ---------------- node-parallel GAT aggregate (bf16 H gather, 8 loads in flight) ----
// Wave = 1 node; half-wave per edge (32 lanes x 1 uint = 128B coalesced row).
// Inner loop: 16 edges / 8 independent H-row loads per iteration (round-16 shape,
// measured best; the 16-load variant regressed on register pressure).
// BF16OUT=1: write packed bf16 rows to out16 (mid-layer T); else fp32 to outf.
template <int BF16OUT>
__global__ void __launch_bounds__(256) k_aggregate(
    const unsigned int* __restrict__ H2, const float* __restrict__ S,
    const float* __restrict__ Dv,
    const int* __restrict__ row_ptr, const int* __restrict__ csr_src,
    const float* __restrict__ bias, float* __restrict__ outf,
    unsigned int* __restrict__ out16, int n) {
    int wave = threadIdx.x >> 6, lane = threadIdx.x & 63;
    int node = blockIdx.x * 4 + wave;
    if (node >= n) return;
    int start = row_ptr[node], end = row_ptr[node + 1];
    float dn = Dv[node];
    int half = lane >> 5;
    int col = lane & 31;
    float accL0 = 0.f, accH0 = 0.f, accL1 = 0.f, accH1 = 0.f;
    float zlane = 0.f;
    for (int base = start; base < end; base += 64) {
        int cnt = min(64, end - base);
        int sj = 0;
        float w = 0.f;
        if (lane < cnt) {
            sj = csr_src[base + lane];
            float t = S[sj] + dn;
            t = (t > 0.f) ? t : NEG_SLOPE * t;
            w = __expf(t);
        }
        zlane += w;
        for (int jj = 0; jj < cnt; jj += 16) {
            int i0 = min(jj + 0 + half, 63);
            int i1 = min(jj + 2 + half, 63);
            int i2 = min(jj + 4 + half, 63);
            int i3 = min(jj + 6 + half, 63);
            int i4 = min(jj + 8 + half, 63);
            int i5 = min(jj + 10 + half, 63);
            int i6 = min(jj + 12 + half, 63);
            int i7 = min(jj + 14 + half, 63);
            float w0 = __shfl(w, i0), w1 = __shfl(w, i1);
            float w2 = __shfl(w, i2), w3 = __shfl(w, i3);
            float w4 = __shfl(w, i4), w5 = __shfl(w, i5);
            float w6 = __shfl(w, i6), w7 = __shfl(w, i7);
            int s0 = __shfl(sj, i0), s1 = __shfl(sj, i1);
            int s2 = __shfl(sj, i2), s3 = __shfl(sj, i3);
            int s4 = __shfl(sj, i4), s5 = __shfl(sj, i5);
            int s6 = __shfl(sj, i6), s7 = __shfl(sj, i7);
            unsigned int u0 = H2[(size_t)s0 * 32 + col];
            unsigned int u1 = H2[(size_t)s1 * 32 + col];
            unsigned int u2 = H2[(size_t)s2 * 32 + col];
            unsigned int u3 = H2[(size_t)s3 * 32 + col];
            unsigned int u4 = H2[(size_t)s4 * 32 + col];
            unsigned int u5 = H2[(size_t)s5 * 32 + col];
            unsigned int u6 = H2[(size_t)s6 * 32 + col];
            unsigned int u7 = H2[(size_t)s7 * 32 + col];
            accL0 = fmaf(w0, __uint_as_float(u0 << 16), accL0);
            accH0 = fmaf(w0, __uint_as_float(u0 & 0xFFFF0000u), accH0);
            accL1 = fmaf(w1, __uint_as_float(u1 << 16), accL1);
            accH1 = fmaf(w1, __uint_as_float(u1 & 0xFFFF0000u), accH1);
            accL0 = fmaf(w2, __uint_as_float(u2 << 16), accL0);
            accH0 = fmaf(w2, __uint_as_float(u2 & 0xFFFF0000u), accH0);
            accL1 = fmaf(w3, __uint_as_float(u3 << 16), accL1);
            accH1 = fmaf(w3, __uint_as_float(u3 & 0xFFFF0000u), accH1);
            accL0 = fmaf(w4, __uint_as_float(u4 << 16), accL0);
            accH0 = fmaf(w4, __uint_as_float(u4 & 0xFFFF0000u), accH0);
            accL1 = fmaf(w5, __uint_as_float(u5 << 16), accL1);
            accH1 = fmaf(w5, __uint_as_float(u5 & 0xFFFF0000u), accH1);
            accL0 = fmaf(w6, __uint_as_float(u6 << 16), accL0);
            accH0 = fmaf(w6, __uint_as_float(u6 & 0xFFFF0000u), accH0);
            accL1 = fmaf(w7, __uint_as_float(u7 << 16), accL1);
            accH1 = fmaf(w7, __uint_as_float(u7 & 0xFFFF0000u), accH1);
        }
    }
    float z = wave_red_sum(zlane);
    float accL = accL0 + accL1;
    float accH = accH0 + accH1;
    accL += __shfl_xor(accL, 32);
    accH += __shfl_xor(accH, 32);
    if (half == 0) {
        float2 b2 = ((const float2*)bias)[col];
        float ox = accL / z + b2.x;
        float oy = accH / z + b2.y;
        if (BF16OUT) {
            out16[(size_t)node * 32 + col] = pack2(ox, oy);
        } else {
            float2 o; o.x = ox; o.y = oy;
            ((float2*)outf)[(size_t)node * 32 + col] = o;
        }
    }
}

// ---------------- column stats (sum/sumsq) of bf16 T, SCOP-hashed atomics ----------
__global__ void __launch_bounds__(256) k_colstats16(const unsigned int* __restrict__ T2,
                                                    int n, float* __restrict__ stats) {
    __shared__ float s0a[256], s1a[256], q0a[256], q1a[256];
    int f2 = threadIdx.x & 31;
    int rowgrp = threadIdx.x >> 5;
    float s0 = 0.f, s1 = 0.f, q0 = 0.f, q1 = 0.f;
    for (int r = blockIdx.x * 8 + rowgrp; r < n; r += gridDim.x * 8) {
        unsigned int u = T2[(size_t)r * 32 + f2];
        float a = __uint_as_float(u << 16);
        float b = __uint_as_float(u & 0xFFFF0000u);
        s0 += a; q0 += a * a;
        s1 += b; q1 += b * b;
    }
    s0a[threadIdx.x] = s0; s1a[threadIdx.x] = s1;
    q0a[threadIdx.x] = q0; q1a[threadIdx.x] = q1;
    __syncthreads();
    for (int off = 128; off >= 32; off >>= 1) {
        if (threadIdx.x < off) {
            s0a[threadIdx.x] += s0a[threadIdx.x + off];
            s1a[threadIdx.x] += s1a[threadIdx.x + off];
            q0a[threadIdx.x] += q0a[threadIdx.x + off];
            q1a[threadIdx.x] += q1a[threadIdx.x + off];
        }
        __syncthreads();
    }
    if (threadIdx.x < 32) {
        float* sb = stats + ((blockIdx.x & (SCOP - 1)) << 7);
        atomicAdd(&sb[2 * threadIdx.x + 0], s0a[threadIdx.x]);
        atomicAdd(&sb[2 * threadIdx.x + 1], s1a[threadIdx.x]);
        atomicAdd(&sb[64 + 2 * threadIdx.x + 0], q0a[threadIdx.x]);
        atomicAdd(&sb[64 + 2 * threadIdx.x + 1], q1a[threadIdx.x]);
    }
}

extern "C" void kernel_launch(void* const* d_in, const int* in_sizes, int n_in,
                              void* d_out, int out_size, void* d_ws, size_t ws_size,
                              hipStream_t stream) {
    const float* x        = (const float*)d_in[0];
    const int*   ei       = (const int*)d_in[1];
    const float* W_in     = (const float*)d_in[2];
    const float* a_src_in = (const float*)d_in[3];
    const float* a_dst_in = (const float*)d_in[4];
    const float* b_in     = (const float*)d_in[5];
    const float* W_mid    = (const float*)d_in[6];
    const float* a_src_mid= (const float*)d_in[7];
    const float* a_dst_mid= (const float*)d_in[8];
    const float* b_mid    = (const float*)d_in[9];
    const float* gamma    = (const float*)d_in[10];
    const float* beta     = (const float*)d_in[11];
    const float* W_out    = (const float*)d_in[12];
    const float* a_src_out= (const float*)d_in[13];
    const float* a_dst_out= (const float*)d_in[14];
    const float* b_out    = (const float*)d_in[15];

    int n = in_sizes[0] / 128;   // 50000
    int E = in_sizes[1] / 2;     // 1250000
    const int* srcE = ei;
    const int* dstE = ei + E;
    int NB = (n + BSIZE - 1) >> BSHIFT;   // 391 (<= NBMAX assumed)
    float inv_n = 1.f / (float)n;

    auto alignup = [](size_t v) { return (v + 255) & ~(size_t)255; };
    char* p = (char*)d_ws;
    int* bcnt    = (int*)p; p += alignup(NBMAX * 4);
    float* stats3= (float*)p; p += alignup((size_t)3 * SCOP * 128 * 4);  // zeroed w/ bcnt
    int* bstart  = (int*)p; p += alignup((NBMAX + 1) * 4);
    int* gcursor = (int*)p; p += alignup(NBMAX * 4);
    int* row_ptr = (int*)p; p += alignup((size_t)(n + 1) * 4);
    unsigned int* binned = (unsigned int*)p; p += alignup((size_t)E * 4);
    int* csr     = (int*)p; p += alignup((size_t)(E + n) * 4);
    unsigned int* H2 = (unsigned int*)p; p += alignup((size_t)n * 32 * 4);   // bf16 [n][64]
    unsigned int* T2 = (unsigned int*)p; p += alignup((size_t)n * 32 * 4);   // bf16 T
    float* S     = (float*)p; p += alignup((size_t)n * 4);
    float* Dv    = (float*)p; p += alignup((size_t)n * 4);
    unsigned short* H16 = (unsigned short*)H2;

    // ---- zero bucket counts + 3 hashed layer-stat buffers (contiguous) ----
    int nzero = NBMAX + 3 * SCOP * 128;
    k_zero<<<(nzero + 255) / 256, 256, 0, stream>>>(bcnt, nzero);

    // ---- binned CSR build (edges identical across all 5 layers) ----
    k_bucket_count<<<256, 256, 0, stream>>>(dstE, E / 4, bcnt);
    k_bucket_scan<<<1, 256, 0, stream>>>(bcnt, NB, bstart, gcursor);
    k_bin<<<(E + BIN_CHUNK - 1) / BIN_CHUNK, 1024, 0, stream>>>(srcE, dstE, E, gcursor, binned);
    k_bucket_csr<<<NB, 256, 0, stream>>>(binned, bstart, n, NB, row_ptr, csr);

    int gb = (n + 3) / 4;        // aggregate grid (4 nodes/block)
    int gg = (n + 63) / 64;      // gemm grid (64 nodes/block)

    // ---- input GAT layer (fp32 x input; bf16 T output) ----
    k_gemm<128, 0, 0><<<gg, 256, 0, stream>>>(x, W_in, a_src_in, a_dst_in,
                                              nullptr, nullptr, nullptr, 0.f,
                                              H16, S, Dv, n);
    k_aggregate<1><<<gb, 256, 0, stream>>>(H2, S, Dv, row_ptr, csr, b_in,
                                           nullptr, T2, n);

    // ---- mid layers: gemm (bf16 T input, inline BN) -> aggregate(bf16) -> colstats ----
    for (int l = 0; l < 3; l++) {
        if (l == 0)
            k_gemm<64, 0, 1><<<gg, 256, 0, stream>>>(T2, W_mid, a_src_mid, a_dst_mid,
                                                     nullptr, nullptr, nullptr, 0.f,
                                                     H16, S, Dv, n);
        else
            k_gemm<64, 1, 1><<<gg, 256, 0, stream>>>(T2, W_mid + l * 4096,
                                                     a_src_mid + l * 64, a_dst_mid + l * 64,
                                                     stats3 + (size_t)(l - 1) * SCOP * 128,
                                                     gamma + (l - 1) * 64, beta + (l - 1) * 64,
                                                     inv_n, H16, S, Dv, n);
        k_aggregate<1><<<gb, 256, 0, stream>>>(H2, S, Dv, row_ptr, csr, b_mid + l * 64,
                                               nullptr, T2, n);
        k_colstats16<<<256, 256, 0, stream>>>(T2, n, stats3 + (size_t)l * SCOP * 128);
    }

    // ---- output GAT layer (bf16 T input, inline BN; fp32 output to d_out) ----
    k_gemm<64, 1, 1><<<gg, 256, 0, stream>>>(T2, W_out, a_src_out, a_dst_out,
                                             stats3 + (size_t)2 * SCOP * 128,
                                             gamma + 2 * 64, beta + 2 * 64,
                                             inv_n, H16, S, Dv, n);
    k_aggregate<0><<<gb, 256, 0, stream>>>(H2, S, Dv, row_ptr, csr, b_out,
                                           (float*)d_out, nullptr, n);
}